// Round 1
// baseline (287.472 us; speedup 1.0000x reference)
//
#include <hip/hip_runtime.h>
#include <hip/hip_bf16.h>

// B=2, L=2048, D=1024, H=16, dh=64. fp32 in/out.
// out = softmax((qa@Wq/8) @ (ma@Wk)^T + bias) @ (ma@Wv) @ Wo.
// Round 8: swapped-QK attention (S^T = mfma(K,Q)) -> P stays in registers via
// PV slot permutation (slot (lq,j) <-> key 32m+(j>>2)*16+lq*4+(j&3)); bias
// loads become float4; Ps buffer deleted (LDS 68->34 KB); per-lane scalar l;
// direct b64 epilogue stores; setprio around MFMA clusters.

typedef __attribute__((ext_vector_type(8))) short short8;   // 8 x bf16 fragment
typedef __attribute__((ext_vector_type(4))) short short4v;  // 4 x bf16
typedef __attribute__((ext_vector_type(4))) float float4v;  // 4 x f32

#define BATCH 2
#define LSEQ 2048
#define DMODEL 1024
#define NHEADS 16
#define DHEAD 64
#define MROWS 4096   // B*L
#define QKVLD 3072   // fused QKV C leading dim

// ---------------------------------------------------------------------------
// fp32 -> bf16 bulk convert (qa, ma). grid (2048, 2)
// ---------------------------------------------------------------------------
__global__ __launch_bounds__(256)
void convert_kernel(const float* __restrict__ qa, const float* __restrict__ ma,
                    __hip_bfloat16* __restrict__ qo, __hip_bfloat16* __restrict__ mo)
{
    const size_t i = ((size_t)blockIdx.x * 256 + threadIdx.x) * 8;
    const float* src = blockIdx.y ? ma : qa;
    __hip_bfloat16* dst = blockIdx.y ? mo : qo;
    float4 v0 = *reinterpret_cast<const float4*>(src + i);
    float4 v1 = *reinterpret_cast<const float4*>(src + i + 4);
    union { __hip_bfloat16 h[8]; int4 v; } pk;
    pk.h[0] = (__hip_bfloat16)v0.x; pk.h[1] = (__hip_bfloat16)v0.y;
    pk.h[2] = (__hip_bfloat16)v0.z; pk.h[3] = (__hip_bfloat16)v0.w;
    pk.h[4] = (__hip_bfloat16)v1.x; pk.h[5] = (__hip_bfloat16)v1.y;
    pk.h[6] = (__hip_bfloat16)v1.z; pk.h[7] = (__hip_bfloat16)v1.w;
    *reinterpret_cast<int4*>(dst + i) = pk.v;
}

// ---------------------------------------------------------------------------
// Weight transpose+convert: W[K][N] f32 -> Wt[N][K] bf16. 64x64 tiles.
// grid (16, 16, 4): z=0..2 -> Wq/Wk/Wv into concat Wt[3072][1024]; z=3 -> Wo.
// ---------------------------------------------------------------------------
__global__ __launch_bounds__(256)
void transpose_w_kernel(const float* __restrict__ W0, const float* __restrict__ W1,
                        const float* __restrict__ W2, const float* __restrict__ W3,
                        __hip_bfloat16* __restrict__ T0, __hip_bfloat16* __restrict__ T1,
                        __hip_bfloat16* __restrict__ T2, __hip_bfloat16* __restrict__ T3)
{
    __shared__ __hip_bfloat16 T[64][68];   // [k][n]

    const float* W; __hip_bfloat16* D;
    if      (blockIdx.z == 0) { W = W0; D = T0; }
    else if (blockIdx.z == 1) { W = W1; D = T1; }
    else if (blockIdx.z == 2) { W = W2; D = T2; }
    else                      { W = W3; D = T3; }

    const int t  = threadIdx.x;
    const int n0 = blockIdx.x * 64;
    const int k0 = blockIdx.y * 64;

#pragma unroll
    for (int p = 0; p < 4; ++p) {
        const int r = p * 16 + (t >> 4);
        const int c = (t & 15) * 4;
        float4 v = *reinterpret_cast<const float4*>(&W[(size_t)(k0 + r) * DMODEL + n0 + c]);
        union { __hip_bfloat16 h[4]; ushort4 v; } pk;
        pk.h[0] = (__hip_bfloat16)v.x; pk.h[1] = (__hip_bfloat16)v.y;
        pk.h[2] = (__hip_bfloat16)v.z; pk.h[3] = (__hip_bfloat16)v.w;
        *reinterpret_cast<ushort4*>(&T[r][c]) = pk.v;
    }
    __syncthreads();
#pragma unroll
    for (int p = 0; p < 2; ++p) {
        const int n  = p * 32 + (t & 31);
        const int kc = (t >> 5) * 8;
        union { __hip_bfloat16 h[8]; int4 v; } pk;
#pragma unroll
        for (int j = 0; j < 8; ++j) pk.h[j] = T[kc + j][n];
        *reinterpret_cast<int4*>(&D[(size_t)(n0 + n) * DMODEL + k0 + kc]) = pk.v;
    }
}

// ---------------------------------------------------------------------------
// bf16 GEMM, B-transposed, A selected per n-block (fused QKV support):
// C[M,N] = alpha * A[M,K] @ Bt[N,K]^T, A = (n0 < nsplit) ? A0 : A1.
// 128x128 tile, BK=32, register prefetch of next K-slab during compute.
// ---------------------------------------------------------------------------
__global__ __launch_bounds__(256)
void gemm_bt_kernel(const __hip_bfloat16* __restrict__ A0,
                    const __hip_bfloat16* __restrict__ A1, int nsplit,
                    float alpha0, float alpha1,
                    const __hip_bfloat16* __restrict__ Bt,
                    float* __restrict__ Cf, __hip_bfloat16* __restrict__ Cb,
                    int K, int ldc)
{
    __shared__ __hip_bfloat16 As[128][40];
    __shared__ __hip_bfloat16 Bs[128][40];

    const int t    = threadIdx.x;
    const int w    = t >> 6;
    const int lane = t & 63;
    const int l15  = lane & 15;
    const int lq   = lane >> 4;
    const int m0   = blockIdx.y * 128;
    const int n0   = blockIdx.x * 128;
    const int wm   = (w >> 1) * 64;
    const int wn   = (w & 1) * 64;
    const int sr   = t >> 1;
    const int sc   = (t & 1) * 16;

    const __hip_bfloat16* A = (n0 < nsplit) ? A0 : A1;
    const float alpha = (n0 < nsplit) ? alpha0 : alpha1;

    float4v acc[4][4];
#pragma unroll
    for (int mi = 0; mi < 4; ++mi)
#pragma unroll
        for (int ni = 0; ni < 4; ++ni) acc[mi][ni] = (float4v){0.f, 0.f, 0.f, 0.f};

    const __hip_bfloat16* Arow = A  + (size_t)(m0 + sr) * K + sc;
    const __hip_bfloat16* Brow = Bt + (size_t)(n0 + sr) * K + sc;

    int4 a0 = *reinterpret_cast<const int4*>(Arow);
    int4 a1 = *reinterpret_cast<const int4*>(Arow + 8);
    int4 b0 = *reinterpret_cast<const int4*>(Brow);
    int4 b1 = *reinterpret_cast<const int4*>(Brow + 8);

    for (int k0 = 0; k0 < K; k0 += 32) {
        __syncthreads();
        *reinterpret_cast<int4*>(&As[sr][sc])     = a0;
        *reinterpret_cast<int4*>(&As[sr][sc + 8]) = a1;
        *reinterpret_cast<int4*>(&Bs[sr][sc])     = b0;
        *reinterpret_cast<int4*>(&Bs[sr][sc + 8]) = b1;
        const int kn = (k0 + 32 < K) ? k0 + 32 : k0;
        a0 = *reinterpret_cast<const int4*>(Arow + kn);
        a1 = *reinterpret_cast<const int4*>(Arow + kn + 8);
        b0 = *reinterpret_cast<const int4*>(Brow + kn);
        b1 = *reinterpret_cast<const int4*>(Brow + kn + 8);
        __syncthreads();

        short8 af[4], bf[4];
#pragma unroll
        for (int mi = 0; mi < 4; ++mi)
            af[mi] = *reinterpret_cast<const short8*>(&As[wm + mi * 16 + l15][lq * 8]);
#pragma unroll
        for (int ni = 0; ni < 4; ++ni)
            bf[ni] = *reinterpret_cast<const short8*>(&Bs[wn + ni * 16 + l15][lq * 8]);
#pragma unroll
        for (int mi = 0; mi < 4; ++mi)
#pragma unroll
            for (int ni = 0; ni < 4; ++ni)
                acc[mi][ni] = __builtin_amdgcn_mfma_f32_16x16x32_bf16(
                    af[mi], bf[ni], acc[mi][ni], 0, 0, 0);
    }

#pragma unroll
    for (int mi = 0; mi < 4; ++mi)
#pragma unroll
        for (int ni = 0; ni < 4; ++ni)
#pragma unroll
            for (int r = 0; r < 4; ++r) {
                const int row = m0 + wm + mi * 16 + lq * 4 + r;
                const int col = n0 + wn + ni * 16 + l15;
                const float v = acc[mi][ni][r] * alpha;
                if (Cf) Cf[(size_t)row * ldc + col] = v;
                else    Cb[(size_t)row * ldc + col] = (__hip_bfloat16)v;
            }
}

// ---------------------------------------------------------------------------
// MFMA flash attention, swapped-QK, in-register P. 1D grid 512 (XCD-swizzled),
// 256 threads = 4 waves; wave w owns q-rows [w*32, w*32+32) as 2 groups of 16.
// S^T = mfma(K-frag, Q-frag): lane (lq,l15) holds keys {16c+4lq+r} for q-row
// l15. Bias loads are float4 (keys consecutive per lane). PV uses the MFMA
// K-slot permutation slot(lq,j) <-> key 32m+(j>>2)*16+4lq+(j&3): P fragments
// are lane-local packs, V^T fragments are two ds_read_b64 halves. No Ps LDS,
// no lgkm serialization; l is a per-lane scalar; direct b64 epilogue stores.
// ---------------------------------------------------------------------------
#define KSTR 68
#define PSTR 132

__global__ __launch_bounds__(256)
void attn_mfma_kernel(const __hip_bfloat16* __restrict__ QKV,  // [B*L][3072]
                      const float* __restrict__ bias,
                      __hip_bfloat16* __restrict__ X)          // [B*L][1024]
{
    __shared__ __hip_bfloat16 Ks[128][KSTR];    // [key][dh]     17408 B
    __shared__ __hip_bfloat16 Vt[64][PSTR];     // [dh][key]     16896 B

    const int t   = threadIdx.x;
    const int w   = t >> 6;
    const int l15 = t & 15;
    const int lq  = (t & 63) >> 4;

    // XCD swizzle: pin each (b,h)'s 16 q-tiles to one XCD-class.
    const int bid = blockIdx.x;
    const int r8  = bid & 7;
    const int j   = bid >> 3;            // 0..63
    const int bh  = r8 + 8 * (j >> 4);   // 0..31
    const int q0  = (j & 15) * 128;
    const int b   = bh >> 4;
    const int h   = bh & 15;

    const __hip_bfloat16* Kb = QKV + (size_t)b * LSEQ * QKVLD + 1024 + h * DHEAD;
    const __hip_bfloat16* Vb = Kb + 1024;

    // Q fragments (B-operand: col = l15 -> q-row g*16+l15), loop-invariant
    short8 aq[2][2];
#pragma unroll
    for (int g = 0; g < 2; ++g) {
        const __hip_bfloat16* qrow = QKV +
            (size_t)(b * LSEQ + q0 + w * 32 + g * 16 + l15) * QKVLD + h * DHEAD + lq * 8;
        aq[g][0] = *reinterpret_cast<const short8*>(qrow);
        aq[g][1] = *reinterpret_cast<const short8*>(qrow + 32);
    }

    // bias row base per g: this lane's q-row, key offset lq*4
    const float* bp0 = bias + (size_t)(q0 + w * 32 + l15) * LSEQ + lq * 4;
    const float* bp1 = bp0 + (size_t)16 * LSEQ;

    float lsum[2] = {0.f, 0.f};
    float4v o_acc[2][4];
#pragma unroll
    for (int g = 0; g < 2; ++g)
#pragma unroll
        for (int n = 0; n < 4; ++n) o_acc[g][n] = (float4v){0.f, 0.f, 0.f, 0.f};

    // staging: thread t stages key (rnd*64 + t>>2), dh chunk (t&3)*16
    const int skey = t >> 2;
    const int sdh  = (t & 3) * 16;
    const int g2   = t & 3;

    int4 pk[2][2], pv[2][2];
#pragma unroll
    for (int rnd = 0; rnd < 2; ++rnd) {
        const int key = rnd * 64 + skey;
        const __hip_bfloat16* ks = Kb + (size_t)key * QKVLD + sdh;
        pk[rnd][0] = *reinterpret_cast<const int4*>(ks);
        pk[rnd][1] = *reinterpret_cast<const int4*>(ks + 8);
        const __hip_bfloat16* vs = Vb + (size_t)key * QKVLD + sdh;
        pv[rnd][0] = *reinterpret_cast<const int4*>(vs);
        pv[rnd][1] = *reinterpret_cast<const int4*>(vs + 8);
    }

    for (int kt = 0; kt < LSEQ / 128; ++kt) {
        const int k0 = kt * 128;
        __syncthreads();   // previous tile's Ks/Vt consumers done
#pragma unroll
        for (int rnd = 0; rnd < 2; ++rnd) {
            const int key = rnd * 64 + skey;
            *reinterpret_cast<int4*>(&Ks[key][sdh])     = pk[rnd][0];
            *reinterpret_cast<int4*>(&Ks[key][sdh + 8]) = pk[rnd][1];
            const __hip_bfloat16* vp0 = reinterpret_cast<const __hip_bfloat16*>(&pv[rnd][0]);
            const __hip_bfloat16* vp1 = reinterpret_cast<const __hip_bfloat16*>(&pv[rnd][1]);
            const int vcol = (((key >> 3) ^ g2) << 3) + (key & 7);
#pragma unroll
            for (int jj = 0; jj < 8; ++jj) Vt[sdh + jj][vcol]     = vp0[jj];
#pragma unroll
            for (int jj = 0; jj < 8; ++jj) Vt[sdh + 8 + jj][vcol] = vp1[jj];
        }
        {
            const int knext = (kt + 1 < LSEQ / 128) ? k0 + 128 : k0;
#pragma unroll
            for (int rnd = 0; rnd < 2; ++rnd) {
                const int key = knext + rnd * 64 + skey;
                const __hip_bfloat16* ks = Kb + (size_t)key * QKVLD + sdh;
                pk[rnd][0] = *reinterpret_cast<const int4*>(ks);
                pk[rnd][1] = *reinterpret_cast<const int4*>(ks + 8);
                const __hip_bfloat16* vs = Vb + (size_t)key * QKVLD + sdh;
                pv[rnd][0] = *reinterpret_cast<const int4*>(vs);
                pv[rnd][1] = *reinterpret_cast<const int4*>(vs + 8);
            }
        }
        __syncthreads();

        // 4 chunks of 32 keys: QK -> exp/pack -> PV, all register-resident
#pragma unroll
        for (int m = 0; m < 4; ++m) {
            // S^T chunk: keys 32m..32m+31 (c = 2m, 2m+1)
            short8 bkA0 = *reinterpret_cast<const short8*>(&Ks[(2*m)    *16 + l15][lq * 8]);
            short8 bkA1 = *reinterpret_cast<const short8*>(&Ks[(2*m)    *16 + l15][32 + lq * 8]);
            short8 bkB0 = *reinterpret_cast<const short8*>(&Ks[(2*m + 1)*16 + l15][lq * 8]);
            short8 bkB1 = *reinterpret_cast<const short8*>(&Ks[(2*m + 1)*16 + l15][32 + lq * 8]);
            float4v sA[2], sB[2];
#pragma unroll
            for (int g = 0; g < 2; ++g) {
                sA[g] = (float4v){0.f, 0.f, 0.f, 0.f};
                sB[g] = (float4v){0.f, 0.f, 0.f, 0.f};
            }
            __builtin_amdgcn_s_setprio(1);
#pragma unroll
            for (int g = 0; g < 2; ++g) {
                sA[g] = __builtin_amdgcn_mfma_f32_16x16x32_bf16(bkA0, aq[g][0], sA[g], 0, 0, 0);
                sA[g] = __builtin_amdgcn_mfma_f32_16x16x32_bf16(bkA1, aq[g][1], sA[g], 0, 0, 0);
                sB[g] = __builtin_amdgcn_mfma_f32_16x16x32_bf16(bkB0, aq[g][0], sB[g], 0, 0, 0);
                sB[g] = __builtin_amdgcn_mfma_f32_16x16x32_bf16(bkB1, aq[g][1], sB[g], 0, 0, 0);
            }
            __builtin_amdgcn_s_setprio(0);

            // p = exp(s + bias); lane-local pack into PV B-fragment.
            // pf element j: key 32m + (j>>2)*16 + 4lq + (j&3)
            short8 pf[2];
#pragma unroll
            for (int g = 0; g < 2; ++g) {
                const float* bp = g ? bp1 : bp0;
                float4v bvA = *reinterpret_cast<const float4v*>(bp + k0 + (2*m)     * 16);
                float4v bvB = *reinterpret_cast<const float4v*>(bp + k0 + (2*m + 1) * 16);
                union { __hip_bfloat16 hh[8]; short8 v; } pp;
#pragma unroll
                for (int r = 0; r < 4; ++r) {
                    const float e = __expf(sA[g][r] + bvA[r]);
                    lsum[g] += e;
                    pp.hh[r] = (__hip_bfloat16)e;
                }
#pragma unroll
                for (int r = 0; r < 4; ++r) {
                    const float e = __expf(sB[g][r] + bvB[r]);
                    lsum[g] += e;
                    pp.hh[4 + r] = (__hip_bfloat16)e;
                }
                pf[g] = pp.v;
            }

            // V^T fragments: slot (lq,j<4) -> keys 32m+4lq+{0..3},
            //                slot (lq,j>=4) -> keys 32m+16+4lq+{0..3}
            short8 vt[4];
#pragma unroll
            for (int n = 0; n < 4; ++n) {
                const int c0 = (((4*m +     (lq >> 1)) ^ n) << 3) + ((lq & 1) << 2);
                const int c1 = (((4*m + 2 + (lq >> 1)) ^ n) << 3) + ((lq & 1) << 2);
                union { short4v h[2]; short8 v; } u;
                u.h[0] = *reinterpret_cast<const short4v*>(&Vt[n * 16 + l15][c0]);
                u.h[1] = *reinterpret_cast<const short4v*>(&Vt[n * 16 + l15][c1]);
                vt[n] = u.v;
            }
            __builtin_amdgcn_s_setprio(1);
#pragma unroll
            for (int g = 0; g < 2; ++g)
#pragma unroll
                for (int n = 0; n < 4; ++n)
                    o_acc[g][n] = __builtin_amdgcn_mfma_f32_16x16x32_bf16(
                        vt[n], pf[g], o_acc[g][n], 0, 0, 0);
            __builtin_amdgcn_s_setprio(0);
        }
    }

    // finalize l across the 4 lq groups sharing each q-row, then store.
    // o_acc[g][n]: D row = d = 16n + 4lq + r, col = q = l15 (lane-local).
#pragma unroll
    for (int g = 0; g < 2; ++g) {
        lsum[g] += __shfl_xor(lsum[g], 16);
        lsum[g] += __shfl_xor(lsum[g], 32);
        const float inv = 1.f / lsum[g];
        const int row = q0 + w * 32 + g * 16 + l15;
        __hip_bfloat16* dst = X + (size_t)(b * LSEQ + row) * DMODEL + h * DHEAD + lq * 4;
#pragma unroll
        for (int n = 0; n < 4; ++n) {
            union { __hip_bfloat16 hh[4]; short4v v; } o;
#pragma unroll
            for (int r = 0; r < 4; ++r) o.hh[r] = (__hip_bfloat16)(o_acc[g][n][r] * inv);
            *reinterpret_cast<short4v*>(dst + n * 16) = o.v;
        }
    }
}

// ---------------------------------------------------------------------------
extern "C" void kernel_launch(void* const* d_in, const int* in_sizes, int n_in,
                              void* d_out, int out_size, void* d_ws, size_t ws_size,
                              hipStream_t stream)
{
    const float* qa   = (const float*)d_in[0];
    const float* ma   = (const float*)d_in[1];
    const float* bias = (const float*)d_in[2];
    const float* Wq   = (const float*)d_in[3];
    const float* Wk   = (const float*)d_in[4];
    const float* Wv   = (const float*)d_in[5];
    const float* Wo   = (const float*)d_in[6];
    float* out = (float*)d_out;

    // ws layout (48 MB): [0,8) qa16/Xw | [8,16) ma16 | [16,22) Wt | [22,24) Wot
    //                    | [24,48) QKVw[4096][3072]
    char* wsb = (char*)d_ws;
    __hip_bfloat16* qa16 = (__hip_bfloat16*)(wsb);
    __hip_bfloat16* ma16 = (__hip_bfloat16*)(wsb + (8u << 20));
    __hip_bfloat16* Wt   = (__hip_bfloat16*)(wsb + (16u << 20));
    __hip_bfloat16* Wot  = (__hip_bfloat16*)(wsb + (22u << 20));
    __hip_bfloat16* QKVw = (__hip_bfloat16*)(wsb + (24u << 20));
    __hip_bfloat16* Xw   = qa16;   // qa16 dead after QKV GEMM

    convert_kernel<<<dim3(MROWS * DMODEL / (256 * 8), 2), 256, 0, stream>>>(
        qa, ma, qa16, ma16);

    transpose_w_kernel<<<dim3(16, 16, 4), 256, 0, stream>>>(
        Wq, Wk, Wv, Wo,
        Wt, Wt + (size_t)DMODEL * DMODEL, Wt + 2 * (size_t)DMODEL * DMODEL, Wot);

    gemm_bt_kernel<<<dim3(QKVLD / 128, MROWS / 128), 256, 0, stream>>>(
        qa16, ma16, DMODEL, 0.125f, 1.0f, Wt, nullptr, QKVw, DMODEL, QKVLD);

    attn_mfma_kernel<<<dim3(512), 256, 0, stream>>>(QKVw, bias, Xw);

    gemm_bt_kernel<<<dim3(DMODEL / 128, MROWS / 128), 256, 0, stream>>>(
        Xw, Xw, DMODEL + 1, 1.0f, 1.0f, Wot, out, nullptr, DMODEL, DMODEL);
}

// Round 2
// 245.982 us; speedup vs baseline: 1.1687x; 1.1687x over previous
//
#include <hip/hip_runtime.h>
#include <hip/hip_bf16.h>

// B=2, L=2048, D=1024, H=16, dh=64. fp32 in/out.
// out = softmax((qa@Wq/8) @ (ma@Wk)^T + bias) @ (ma@Wv) @ Wo.
// Round 9: 8-wave attention blocks (512 thr), wave owns 16 q-rows ->
// 16 waves/CU (4/SIMD) TLP; VGPR capped 128 via __launch_bounds__(512,4).
// Vt stored in PV-slot order with per-rowgroup ^a XOR -> single b128 V-frag
// reads, conflict-free (R7-measured pattern). Register P (swapped QK) kept.

typedef __attribute__((ext_vector_type(8))) short short8;   // 8 x bf16 fragment
typedef __attribute__((ext_vector_type(4))) short short4v;  // 4 x bf16
typedef __attribute__((ext_vector_type(4))) float float4v;  // 4 x f32

#define BATCH 2
#define LSEQ 2048
#define DMODEL 1024
#define NHEADS 16
#define DHEAD 64
#define MROWS 4096   // B*L
#define QKVLD 3072   // fused QKV C leading dim

// ---------------------------------------------------------------------------
// fp32 -> bf16 bulk convert (qa, ma). grid (2048, 2)
// ---------------------------------------------------------------------------
__global__ __launch_bounds__(256)
void convert_kernel(const float* __restrict__ qa, const float* __restrict__ ma,
                    __hip_bfloat16* __restrict__ qo, __hip_bfloat16* __restrict__ mo)
{
    const size_t i = ((size_t)blockIdx.x * 256 + threadIdx.x) * 8;
    const float* src = blockIdx.y ? ma : qa;
    __hip_bfloat16* dst = blockIdx.y ? mo : qo;
    float4 v0 = *reinterpret_cast<const float4*>(src + i);
    float4 v1 = *reinterpret_cast<const float4*>(src + i + 4);
    union { __hip_bfloat16 h[8]; int4 v; } pk;
    pk.h[0] = (__hip_bfloat16)v0.x; pk.h[1] = (__hip_bfloat16)v0.y;
    pk.h[2] = (__hip_bfloat16)v0.z; pk.h[3] = (__hip_bfloat16)v0.w;
    pk.h[4] = (__hip_bfloat16)v1.x; pk.h[5] = (__hip_bfloat16)v1.y;
    pk.h[6] = (__hip_bfloat16)v1.z; pk.h[7] = (__hip_bfloat16)v1.w;
    *reinterpret_cast<int4*>(dst + i) = pk.v;
}

// ---------------------------------------------------------------------------
// Weight transpose+convert: W[K][N] f32 -> Wt[N][K] bf16. 64x64 tiles.
// grid (16, 16, 4): z=0..2 -> Wq/Wk/Wv into concat Wt[3072][1024]; z=3 -> Wo.
// ---------------------------------------------------------------------------
__global__ __launch_bounds__(256)
void transpose_w_kernel(const float* __restrict__ W0, const float* __restrict__ W1,
                        const float* __restrict__ W2, const float* __restrict__ W3,
                        __hip_bfloat16* __restrict__ T0, __hip_bfloat16* __restrict__ T1,
                        __hip_bfloat16* __restrict__ T2, __hip_bfloat16* __restrict__ T3)
{
    __shared__ __hip_bfloat16 T[64][68];   // [k][n]

    const float* W; __hip_bfloat16* D;
    if      (blockIdx.z == 0) { W = W0; D = T0; }
    else if (blockIdx.z == 1) { W = W1; D = T1; }
    else if (blockIdx.z == 2) { W = W2; D = T2; }
    else                      { W = W3; D = T3; }

    const int t  = threadIdx.x;
    const int n0 = blockIdx.x * 64;
    const int k0 = blockIdx.y * 64;

#pragma unroll
    for (int p = 0; p < 4; ++p) {
        const int r = p * 16 + (t >> 4);
        const int c = (t & 15) * 4;
        float4 v = *reinterpret_cast<const float4*>(&W[(size_t)(k0 + r) * DMODEL + n0 + c]);
        union { __hip_bfloat16 h[4]; ushort4 v; } pk;
        pk.h[0] = (__hip_bfloat16)v.x; pk.h[1] = (__hip_bfloat16)v.y;
        pk.h[2] = (__hip_bfloat16)v.z; pk.h[3] = (__hip_bfloat16)v.w;
        *reinterpret_cast<ushort4*>(&T[r][c]) = pk.v;
    }
    __syncthreads();
#pragma unroll
    for (int p = 0; p < 2; ++p) {
        const int n  = p * 32 + (t & 31);
        const int kc = (t >> 5) * 8;
        union { __hip_bfloat16 h[8]; int4 v; } pk;
#pragma unroll
        for (int j = 0; j < 8; ++j) pk.h[j] = T[kc + j][n];
        *reinterpret_cast<int4*>(&D[(size_t)(n0 + n) * DMODEL + k0 + kc]) = pk.v;
    }
}

// ---------------------------------------------------------------------------
// bf16 GEMM, B-transposed, A selected per n-block (fused QKV support):
// C[M,N] = alpha * A[M,K] @ Bt[N,K]^T, A = (n0 < nsplit) ? A0 : A1.
// 128x128 tile, BK=32, register prefetch of next K-slab during compute.
// ---------------------------------------------------------------------------
__global__ __launch_bounds__(256)
void gemm_bt_kernel(const __hip_bfloat16* __restrict__ A0,
                    const __hip_bfloat16* __restrict__ A1, int nsplit,
                    float alpha0, float alpha1,
                    const __hip_bfloat16* __restrict__ Bt,
                    float* __restrict__ Cf, __hip_bfloat16* __restrict__ Cb,
                    int K, int ldc)
{
    __shared__ __hip_bfloat16 As[128][40];
    __shared__ __hip_bfloat16 Bs[128][40];

    const int t    = threadIdx.x;
    const int w    = t >> 6;
    const int lane = t & 63;
    const int l15  = lane & 15;
    const int lq   = lane >> 4;
    const int m0   = blockIdx.y * 128;
    const int n0   = blockIdx.x * 128;
    const int wm   = (w >> 1) * 64;
    const int wn   = (w & 1) * 64;
    const int sr   = t >> 1;
    const int sc   = (t & 1) * 16;

    const __hip_bfloat16* A = (n0 < nsplit) ? A0 : A1;
    const float alpha = (n0 < nsplit) ? alpha0 : alpha1;

    float4v acc[4][4];
#pragma unroll
    for (int mi = 0; mi < 4; ++mi)
#pragma unroll
        for (int ni = 0; ni < 4; ++ni) acc[mi][ni] = (float4v){0.f, 0.f, 0.f, 0.f};

    const __hip_bfloat16* Arow = A  + (size_t)(m0 + sr) * K + sc;
    const __hip_bfloat16* Brow = Bt + (size_t)(n0 + sr) * K + sc;

    int4 a0 = *reinterpret_cast<const int4*>(Arow);
    int4 a1 = *reinterpret_cast<const int4*>(Arow + 8);
    int4 b0 = *reinterpret_cast<const int4*>(Brow);
    int4 b1 = *reinterpret_cast<const int4*>(Brow + 8);

    for (int k0 = 0; k0 < K; k0 += 32) {
        __syncthreads();
        *reinterpret_cast<int4*>(&As[sr][sc])     = a0;
        *reinterpret_cast<int4*>(&As[sr][sc + 8]) = a1;
        *reinterpret_cast<int4*>(&Bs[sr][sc])     = b0;
        *reinterpret_cast<int4*>(&Bs[sr][sc + 8]) = b1;
        const int kn = (k0 + 32 < K) ? k0 + 32 : k0;
        a0 = *reinterpret_cast<const int4*>(Arow + kn);
        a1 = *reinterpret_cast<const int4*>(Arow + kn + 8);
        b0 = *reinterpret_cast<const int4*>(Brow + kn);
        b1 = *reinterpret_cast<const int4*>(Brow + kn + 8);
        __syncthreads();

        short8 af[4], bf[4];
#pragma unroll
        for (int mi = 0; mi < 4; ++mi)
            af[mi] = *reinterpret_cast<const short8*>(&As[wm + mi * 16 + l15][lq * 8]);
#pragma unroll
        for (int ni = 0; ni < 4; ++ni)
            bf[ni] = *reinterpret_cast<const short8*>(&Bs[wn + ni * 16 + l15][lq * 8]);
#pragma unroll
        for (int mi = 0; mi < 4; ++mi)
#pragma unroll
            for (int ni = 0; ni < 4; ++ni)
                acc[mi][ni] = __builtin_amdgcn_mfma_f32_16x16x32_bf16(
                    af[mi], bf[ni], acc[mi][ni], 0, 0, 0);
    }

#pragma unroll
    for (int mi = 0; mi < 4; ++mi)
#pragma unroll
        for (int ni = 0; ni < 4; ++ni)
#pragma unroll
            for (int r = 0; r < 4; ++r) {
                const int row = m0 + wm + mi * 16 + lq * 4 + r;
                const int col = n0 + wn + ni * 16 + l15;
                const float v = acc[mi][ni][r] * alpha;
                if (Cf) Cf[(size_t)row * ldc + col] = v;
                else    Cb[(size_t)row * ldc + col] = (__hip_bfloat16)v;
            }
}

// ---------------------------------------------------------------------------
// MFMA flash attention, swapped-QK, in-register P. Grid 512 (XCD-swizzled),
// 512 threads = 8 waves; wave w owns q-rows [w*16, w*16+16).
// S^T = mfma(K-frag, Q-frag): lane (lq,l15) holds keys {16c+4lq+r} for q-row
// l15; bias loads are float4. PV slot permutation slot(lq,j) <-> key
// 32m+(j>>2)*16+4lq+(j&3); Vt is stored in slot order (col = ((cblk^a)<<3)
// + hi*4 + r, cblk = (key>>5)*4+((key>>2)&3), a = row-group) so the V-frag
// is ONE b128 read with the R7-verified conflict-free ^n bank pattern.
// 2 blocks/CU x 8 waves = 16 waves/CU for latency hiding.
// ---------------------------------------------------------------------------
#define KSTR 68
#define PSTR 132

__global__ __launch_bounds__(512, 4)
void attn_mfma_kernel(const __hip_bfloat16* __restrict__ QKV,  // [B*L][3072]
                      const float* __restrict__ bias,
                      __hip_bfloat16* __restrict__ X)          // [B*L][1024]
{
    __shared__ __hip_bfloat16 Ks[128][KSTR];    // [key][dh]     17408 B
    __shared__ __hip_bfloat16 Vt[64][PSTR];     // [dh][slot]    16896 B

    const int t   = threadIdx.x;
    const int w   = t >> 6;            // 0..7
    const int l15 = t & 15;
    const int lq  = (t & 63) >> 4;

    // XCD swizzle: pin each (b,h)'s 16 q-tiles to one XCD-class.
    const int bid = blockIdx.x;
    const int r8  = bid & 7;
    const int j   = bid >> 3;            // 0..63
    const int bh  = r8 + 8 * (j >> 4);   // 0..31
    const int q0  = (j & 15) * 128;
    const int b   = bh >> 4;
    const int h   = bh & 15;

    const __hip_bfloat16* Kb = QKV + (size_t)b * LSEQ * QKVLD + 1024 + h * DHEAD;
    const __hip_bfloat16* Vb = Kb + 1024;

    // Q fragments (B-operand: col = l15 -> q-row w*16+l15), loop-invariant
    short8 aq[2];
    {
        const __hip_bfloat16* qrow = QKV +
            (size_t)(b * LSEQ + q0 + w * 16 + l15) * QKVLD + h * DHEAD + lq * 8;
        aq[0] = *reinterpret_cast<const short8*>(qrow);
        aq[1] = *reinterpret_cast<const short8*>(qrow + 32);
    }

    // bias row base: this lane's q-row, key offset lq*4
    const float* bp = bias + (size_t)(q0 + w * 16 + l15) * LSEQ + lq * 4;

    float lsum = 0.f;
    float4v o_acc[4];
#pragma unroll
    for (int n = 0; n < 4; ++n) o_acc[n] = (float4v){0.f, 0.f, 0.f, 0.f};

    // staging: thread t stages key (t>>2), dh chunk (t&3)*16, row-group a=t&3
    const int skey = t >> 2;           // 0..127
    const int sdh  = (t & 3) * 16;
    const int a    = t & 3;
    // slot-order column for this key (constant across the 16 rows staged)
    const int cblk = ((skey >> 5) << 2) | ((skey >> 2) & 3);
    const int vcol = (((cblk ^ a) << 3)) | ((((skey >> 4) & 1) << 2)) | (skey & 3);

    int4 pk0, pk1, pv0, pv1;
    {
        const __hip_bfloat16* ks = Kb + (size_t)skey * QKVLD + sdh;
        pk0 = *reinterpret_cast<const int4*>(ks);
        pk1 = *reinterpret_cast<const int4*>(ks + 8);
        const __hip_bfloat16* vs = Vb + (size_t)skey * QKVLD + sdh;
        pv0 = *reinterpret_cast<const int4*>(vs);
        pv1 = *reinterpret_cast<const int4*>(vs + 8);
    }

    for (int kt = 0; kt < LSEQ / 128; ++kt) {
        const int k0 = kt * 128;
        __syncthreads();   // previous tile's Ks/Vt consumers done
        *reinterpret_cast<int4*>(&Ks[skey][sdh])     = pk0;
        *reinterpret_cast<int4*>(&Ks[skey][sdh + 8]) = pk1;
        {
            const __hip_bfloat16* vp0 = reinterpret_cast<const __hip_bfloat16*>(&pv0);
            const __hip_bfloat16* vp1 = reinterpret_cast<const __hip_bfloat16*>(&pv1);
#pragma unroll
            for (int jj = 0; jj < 8; ++jj) Vt[sdh + jj][vcol]     = vp0[jj];
#pragma unroll
            for (int jj = 0; jj < 8; ++jj) Vt[sdh + 8 + jj][vcol] = vp1[jj];
        }
        {
            const int knext = (kt + 1 < LSEQ / 128) ? k0 + 128 : k0;
            const __hip_bfloat16* ks = Kb + (size_t)(knext + skey) * QKVLD + sdh;
            pk0 = *reinterpret_cast<const int4*>(ks);
            pk1 = *reinterpret_cast<const int4*>(ks + 8);
            const __hip_bfloat16* vs = Vb + (size_t)(knext + skey) * QKVLD + sdh;
            pv0 = *reinterpret_cast<const int4*>(vs);
            pv1 = *reinterpret_cast<const int4*>(vs + 8);
        }
        __syncthreads();

        // 4 chunks of 32 keys: QK -> exp/pack -> PV, all register-resident
#pragma unroll
        for (int m = 0; m < 4; ++m) {
            short8 bkA0 = *reinterpret_cast<const short8*>(&Ks[(2*m)    *16 + l15][lq * 8]);
            short8 bkA1 = *reinterpret_cast<const short8*>(&Ks[(2*m)    *16 + l15][32 + lq * 8]);
            short8 bkB0 = *reinterpret_cast<const short8*>(&Ks[(2*m + 1)*16 + l15][lq * 8]);
            short8 bkB1 = *reinterpret_cast<const short8*>(&Ks[(2*m + 1)*16 + l15][32 + lq * 8]);
            float4v bvA = *reinterpret_cast<const float4v*>(bp + k0 + 32 * m);
            float4v bvB = *reinterpret_cast<const float4v*>(bp + k0 + 32 * m + 16);

            float4v sA = (float4v){0.f, 0.f, 0.f, 0.f};
            float4v sB = (float4v){0.f, 0.f, 0.f, 0.f};
            __builtin_amdgcn_s_setprio(1);
            sA = __builtin_amdgcn_mfma_f32_16x16x32_bf16(bkA0, aq[0], sA, 0, 0, 0);
            sA = __builtin_amdgcn_mfma_f32_16x16x32_bf16(bkA1, aq[1], sA, 0, 0, 0);
            sB = __builtin_amdgcn_mfma_f32_16x16x32_bf16(bkB0, aq[0], sB, 0, 0, 0);
            sB = __builtin_amdgcn_mfma_f32_16x16x32_bf16(bkB1, aq[1], sB, 0, 0, 0);
            __builtin_amdgcn_s_setprio(0);

            // p = exp(s + bias); lane-local pack into PV B-fragment.
            // pf element j: key 32m + (j>>2)*16 + 4lq + (j&3)
            union { __hip_bfloat16 hh[8]; short8 v; } pp;
#pragma unroll
            for (int r = 0; r < 4; ++r) {
                const float e = __expf(sA[r] + bvA[r]);
                lsum += e;
                pp.hh[r] = (__hip_bfloat16)e;
            }
#pragma unroll
            for (int r = 0; r < 4; ++r) {
                const float e = __expf(sB[r] + bvB[r]);
                lsum += e;
                pp.hh[4 + r] = (__hip_bfloat16)e;
            }
            const short8 pf = pp.v;

            // V^T fragments, slot order: one b128 per n, ^n XOR bank pattern
            short8 vt[4];
#pragma unroll
            for (int n = 0; n < 4; ++n)
                vt[n] = *reinterpret_cast<const short8*>(
                    &Vt[n * 16 + l15][((m * 4 + lq) ^ n) << 3]);

            __builtin_amdgcn_s_setprio(1);
#pragma unroll
            for (int n = 0; n < 4; ++n)
                o_acc[n] = __builtin_amdgcn_mfma_f32_16x16x32_bf16(
                    vt[n], pf, o_acc[n], 0, 0, 0);
            __builtin_amdgcn_s_setprio(0);
        }
    }

    // finalize l across the 4 lq groups sharing each q-row, then store.
    lsum += __shfl_xor(lsum, 16);
    lsum += __shfl_xor(lsum, 32);
    const float inv = 1.f / lsum;
    {
        const int row = q0 + w * 16 + l15;
        __hip_bfloat16* dst = X + (size_t)(b * LSEQ + row) * DMODEL + h * DHEAD + lq * 4;
#pragma unroll
        for (int n = 0; n < 4; ++n) {
            union { __hip_bfloat16 hh[4]; short4v v; } o;
#pragma unroll
            for (int r = 0; r < 4; ++r) o.hh[r] = (__hip_bfloat16)(o_acc[n][r] * inv);
            *reinterpret_cast<short4v*>(dst + n * 16) = o.v;
        }
    }
}

// ---------------------------------------------------------------------------
extern "C" void kernel_launch(void* const* d_in, const int* in_sizes, int n_in,
                              void* d_out, int out_size, void* d_ws, size_t ws_size,
                              hipStream_t stream)
{
    const float* qa   = (const float*)d_in[0];
    const float* ma   = (const float*)d_in[1];
    const float* bias = (const float*)d_in[2];
    const float* Wq   = (const float*)d_in[3];
    const float* Wk   = (const float*)d_in[4];
    const float* Wv   = (const float*)d_in[5];
    const float* Wo   = (const float*)d_in[6];
    float* out = (float*)d_out;

    // ws layout (48 MB): [0,8) qa16/Xw | [8,16) ma16 | [16,22) Wt | [22,24) Wot
    //                    | [24,48) QKVw[4096][3072]
    char* wsb = (char*)d_ws;
    __hip_bfloat16* qa16 = (__hip_bfloat16*)(wsb);
    __hip_bfloat16* ma16 = (__hip_bfloat16*)(wsb + (8u << 20));
    __hip_bfloat16* Wt   = (__hip_bfloat16*)(wsb + (16u << 20));
    __hip_bfloat16* Wot  = (__hip_bfloat16*)(wsb + (22u << 20));
    __hip_bfloat16* QKVw = (__hip_bfloat16*)(wsb + (24u << 20));
    __hip_bfloat16* Xw   = qa16;   // qa16 dead after QKV GEMM

    convert_kernel<<<dim3(MROWS * DMODEL / (256 * 8), 2), 256, 0, stream>>>(
        qa, ma, qa16, ma16);

    transpose_w_kernel<<<dim3(16, 16, 4), 256, 0, stream>>>(
        Wq, Wk, Wv, Wo,
        Wt, Wt + (size_t)DMODEL * DMODEL, Wt + 2 * (size_t)DMODEL * DMODEL, Wot);

    gemm_bt_kernel<<<dim3(QKVLD / 128, MROWS / 128), 256, 0, stream>>>(
        qa16, ma16, DMODEL, 0.125f, 1.0f, Wt, nullptr, QKVw, DMODEL, QKVLD);

    attn_mfma_kernel<<<dim3(512), 512, 0, stream>>>(QKVw, bias, Xw);

    gemm_bt_kernel<<<dim3(DMODEL / 128, MROWS / 128), 256, 0, stream>>>(
        Xw, Xw, DMODEL + 1, 1.0f, 1.0f, Wot, out, nullptr, DMODEL, DMODEL);
}

// Round 3
// 240.849 us; speedup vs baseline: 1.1936x; 1.0213x over previous
//
#include <hip/hip_runtime.h>
#include <hip/hip_bf16.h>

// B=2, L=2048, D=1024, H=16, dh=64. fp32 in/out.
// out = softmax((qa@Wq/8) @ (ma@Wk)^T + bias) @ (ma@Wv) @ Wo.
// Round 10: GEMMs rebuilt on the m97 structure (BK=64, unpadded LDS,
// global_load_lds dwordx4 with pre-swizzled global source + chunk^row XOR
// reads, 2-barrier K-step, XCD-chunked m-sliced block map). Attn: Vt swizzle
// family changed to ^(a<<2) so the 16-way scatter store spreads over 16 banks
// (2-way merged = free); read side ^(n<<2) cancels identically.

typedef __attribute__((ext_vector_type(8))) short short8;   // 8 x bf16 fragment
typedef __attribute__((ext_vector_type(4))) short short4v;  // 4 x bf16
typedef __attribute__((ext_vector_type(4))) float float4v;  // 4 x f32

#define BATCH 2
#define LSEQ 2048
#define DMODEL 1024
#define NHEADS 16
#define DHEAD 64
#define MROWS 4096   // B*L
#define QKVLD 3072   // fused QKV C leading dim

// ---------------------------------------------------------------------------
// fp32 -> bf16 bulk convert (qa, ma). grid (2048, 2)
// ---------------------------------------------------------------------------
__global__ __launch_bounds__(256)
void convert_kernel(const float* __restrict__ qa, const float* __restrict__ ma,
                    __hip_bfloat16* __restrict__ qo, __hip_bfloat16* __restrict__ mo)
{
    const size_t i = ((size_t)blockIdx.x * 256 + threadIdx.x) * 8;
    const float* src = blockIdx.y ? ma : qa;
    __hip_bfloat16* dst = blockIdx.y ? mo : qo;
    float4 v0 = *reinterpret_cast<const float4*>(src + i);
    float4 v1 = *reinterpret_cast<const float4*>(src + i + 4);
    union { __hip_bfloat16 h[8]; int4 v; } pk;
    pk.h[0] = (__hip_bfloat16)v0.x; pk.h[1] = (__hip_bfloat16)v0.y;
    pk.h[2] = (__hip_bfloat16)v0.z; pk.h[3] = (__hip_bfloat16)v0.w;
    pk.h[4] = (__hip_bfloat16)v1.x; pk.h[5] = (__hip_bfloat16)v1.y;
    pk.h[6] = (__hip_bfloat16)v1.z; pk.h[7] = (__hip_bfloat16)v1.w;
    *reinterpret_cast<int4*>(dst + i) = pk.v;
}

// ---------------------------------------------------------------------------
// Weight transpose+convert: W[K][N] f32 -> Wt[N][K] bf16. 64x64 tiles.
// grid (16, 16, 4): z=0..2 -> Wq/Wk/Wv into concat Wt[3072][1024]; z=3 -> Wo.
// ---------------------------------------------------------------------------
__global__ __launch_bounds__(256)
void transpose_w_kernel(const float* __restrict__ W0, const float* __restrict__ W1,
                        const float* __restrict__ W2, const float* __restrict__ W3,
                        __hip_bfloat16* __restrict__ T0, __hip_bfloat16* __restrict__ T1,
                        __hip_bfloat16* __restrict__ T2, __hip_bfloat16* __restrict__ T3)
{
    __shared__ __hip_bfloat16 T[64][68];   // [k][n]

    const float* W; __hip_bfloat16* D;
    if      (blockIdx.z == 0) { W = W0; D = T0; }
    else if (blockIdx.z == 1) { W = W1; D = T1; }
    else if (blockIdx.z == 2) { W = W2; D = T2; }
    else                      { W = W3; D = T3; }

    const int t  = threadIdx.x;
    const int n0 = blockIdx.x * 64;
    const int k0 = blockIdx.y * 64;

#pragma unroll
    for (int p = 0; p < 4; ++p) {
        const int r = p * 16 + (t >> 4);
        const int c = (t & 15) * 4;
        float4 v = *reinterpret_cast<const float4*>(&W[(size_t)(k0 + r) * DMODEL + n0 + c]);
        union { __hip_bfloat16 h[4]; ushort4 v; } pk;
        pk.h[0] = (__hip_bfloat16)v.x; pk.h[1] = (__hip_bfloat16)v.y;
        pk.h[2] = (__hip_bfloat16)v.z; pk.h[3] = (__hip_bfloat16)v.w;
        *reinterpret_cast<ushort4*>(&T[r][c]) = pk.v;
    }
    __syncthreads();
#pragma unroll
    for (int p = 0; p < 2; ++p) {
        const int n  = p * 32 + (t & 31);
        const int kc = (t >> 5) * 8;
        union { __hip_bfloat16 h[8]; int4 v; } pk;
#pragma unroll
        for (int j = 0; j < 8; ++j) pk.h[j] = T[kc + j][n];
        *reinterpret_cast<int4*>(&D[(size_t)(n0 + n) * DMODEL + k0 + kc]) = pk.v;
    }
}

// ---------------------------------------------------------------------------
// bf16 GEMM, B-transposed, m97 structure. C[M,N] = alpha * A[M,K] @ Bt[N,K]^T,
// A = (n0 < nsplit) ? A0 : A1. 128x128 tile, BK=64, 4 waves.
// Staging: global_load_lds dwordx4, linear LDS dest, per-lane global source
// pre-swizzled chunk = (l&7)^((l>>3)&7); frag reads use chunk^(row&7).
// 1D grid (multiple of 8), XCD-chunked: each XCD owns contiguous m-panels.
// ---------------------------------------------------------------------------
#define GBK 64

__global__ __launch_bounds__(256, 2)
void gemm_bt_kernel(const __hip_bfloat16* __restrict__ A0,
                    const __hip_bfloat16* __restrict__ A1, int nsplit,
                    float alpha0, float alpha1,
                    const __hip_bfloat16* __restrict__ Bt,
                    float* __restrict__ Cf, __hip_bfloat16* __restrict__ Cb,
                    int K, int ldc, int nbx)
{
    __shared__ __hip_bfloat16 As[128][GBK];   // 16 KB, chunk-swizzled rows
    __shared__ __hip_bfloat16 Bs[128][GBK];   // 16 KB

    const int t    = threadIdx.x;
    const int w    = t >> 6;
    const int lane = t & 63;
    const int l15  = lane & 15;
    const int lq   = lane >> 4;
    const int wm   = (w >> 1) * 64;
    const int wn   = (w & 1) * 64;

    // XCD-chunked block map: XCD c owns m-tiles [c*mper, (c+1)*mper), n fast.
    const int nwg  = gridDim.x;
    const int c    = blockIdx.x & 7;
    const int q    = blockIdx.x >> 3;
    const int mper = (nwg >> 3) / nbx;
    const int m0   = (c * mper + q / nbx) * 128;
    const int n0   = (q % nbx) * 128;

    const __hip_bfloat16* A = (n0 < nsplit) ? A0 : A1;
    const float alpha = (n0 < nsplit) ? alpha0 : alpha1;

    // staging geometry: wave w, instr i covers rows (w*4+i)*8 .. +8 (128B each)
    const int lrow = lane >> 3;                    // 0..7
    const int lch  = (lane & 7) ^ lrow;            // pre-swizzled source chunk

    float4v acc[4][4];
#pragma unroll
    for (int mi = 0; mi < 4; ++mi)
#pragma unroll
        for (int ni = 0; ni < 4; ++ni) acc[mi][ni] = (float4v){0.f, 0.f, 0.f, 0.f};

    for (int k0 = 0; k0 < K; k0 += GBK) {
        __syncthreads();
#pragma unroll
        for (int i = 0; i < 4; ++i) {
            const int rb = (w * 4 + i) * 8;
            const int r  = rb + lrow;
            __builtin_amdgcn_global_load_lds(
                (const __attribute__((address_space(1))) void*)
                    (A + (size_t)(m0 + r) * K + k0 + lch * 8),
                (__attribute__((address_space(3))) void*)&As[rb][0], 16, 0, 0);
            __builtin_amdgcn_global_load_lds(
                (const __attribute__((address_space(1))) void*)
                    (Bt + (size_t)(n0 + r) * K + k0 + lch * 8),
                (__attribute__((address_space(3))) void*)&Bs[rb][0], 16, 0, 0);
        }
        asm volatile("s_waitcnt vmcnt(0)" ::: "memory");
        __syncthreads();

#pragma unroll
        for (int kh = 0; kh < 2; ++kh) {
            short8 af[4], bf[4];
#pragma unroll
            for (int mi = 0; mi < 4; ++mi) {
                const int r = wm + mi * 16 + l15;
                af[mi] = *reinterpret_cast<const short8*>(
                    &As[r][(((kh << 2) | lq) ^ (r & 7)) << 3]);
            }
#pragma unroll
            for (int ni = 0; ni < 4; ++ni) {
                const int r = wn + ni * 16 + l15;
                bf[ni] = *reinterpret_cast<const short8*>(
                    &Bs[r][(((kh << 2) | lq) ^ (r & 7)) << 3]);
            }
#pragma unroll
            for (int mi = 0; mi < 4; ++mi)
#pragma unroll
                for (int ni = 0; ni < 4; ++ni)
                    acc[mi][ni] = __builtin_amdgcn_mfma_f32_16x16x32_bf16(
                        af[mi], bf[ni], acc[mi][ni], 0, 0, 0);
        }
    }

#pragma unroll
    for (int mi = 0; mi < 4; ++mi)
#pragma unroll
        for (int ni = 0; ni < 4; ++ni)
#pragma unroll
            for (int r = 0; r < 4; ++r) {
                const int row = m0 + wm + mi * 16 + lq * 4 + r;
                const int col = n0 + wn + ni * 16 + l15;
                const float v = acc[mi][ni][r] * alpha;
                if (Cf) Cf[(size_t)row * ldc + col] = v;
                else    Cb[(size_t)row * ldc + col] = (__hip_bfloat16)v;
            }
}

// ---------------------------------------------------------------------------
// MFMA flash attention, swapped-QK, in-register P. Grid 512 (XCD-swizzled),
// 512 threads = 8 waves; wave w owns q-rows [w*16, w*16+16).
// S^T = mfma(K-frag, Q-frag): lane (lq,l15) holds keys {16c+4lq+r} for q-row
// l15; bias loads are float4. PV slot permutation slot(lq,j) <-> key
// 32m+(j>>2)*16+4lq+(j&3); Vt stored in slot order with ^(a<<2) bank swizzle
// (store spreads over 16 banks 2-way-merged = free; read ^(n<<2) cancels).
// 2 blocks/CU x 8 waves = 16 waves/CU for latency hiding.
// ---------------------------------------------------------------------------
#define KSTR 68
#define PSTR 132

__global__ __launch_bounds__(512, 4)
void attn_mfma_kernel(const __hip_bfloat16* __restrict__ QKV,  // [B*L][3072]
                      const float* __restrict__ bias,
                      __hip_bfloat16* __restrict__ X)          // [B*L][1024]
{
    __shared__ __hip_bfloat16 Ks[128][KSTR];    // [key][dh]     17408 B
    __shared__ __hip_bfloat16 Vt[64][PSTR];     // [dh][slot]    16896 B

    const int t   = threadIdx.x;
    const int w   = t >> 6;            // 0..7
    const int l15 = t & 15;
    const int lq  = (t & 63) >> 4;

    // XCD swizzle: pin each (b,h)'s 16 q-tiles to one XCD-class.
    const int bid = blockIdx.x;
    const int r8  = bid & 7;
    const int j   = bid >> 3;            // 0..63
    const int bh  = r8 + 8 * (j >> 4);   // 0..31
    const int q0  = (j & 15) * 128;
    const int b   = bh >> 4;
    const int h   = bh & 15;

    const __hip_bfloat16* Kb = QKV + (size_t)b * LSEQ * QKVLD + 1024 + h * DHEAD;
    const __hip_bfloat16* Vb = Kb + 1024;

    // Q fragments (B-operand: col = l15 -> q-row w*16+l15), loop-invariant
    short8 aq[2];
    {
        const __hip_bfloat16* qrow = QKV +
            (size_t)(b * LSEQ + q0 + w * 16 + l15) * QKVLD + h * DHEAD + lq * 8;
        aq[0] = *reinterpret_cast<const short8*>(qrow);
        aq[1] = *reinterpret_cast<const short8*>(qrow + 32);
    }

    // bias row base: this lane's q-row, key offset lq*4
    const float* bp = bias + (size_t)(q0 + w * 16 + l15) * LSEQ + lq * 4;

    float lsum = 0.f;
    float4v o_acc[4];
#pragma unroll
    for (int n = 0; n < 4; ++n) o_acc[n] = (float4v){0.f, 0.f, 0.f, 0.f};

    // staging: thread t stages key (t>>2), dh chunk (t&3)*16, row-group a=t&3
    const int skey = t >> 2;           // 0..127
    const int sdh  = (t & 3) * 16;
    const int a    = t & 3;
    // slot-order column for this key, bank-spread via ^(a<<2)
    const int cblk = ((skey >> 5) << 2) | ((skey >> 2) & 3);
    const int vcol = (((cblk ^ (a << 2)) << 3)) | ((((skey >> 4) & 1) << 2)) | (skey & 3);

    int4 pk0, pk1, pv0, pv1;
    {
        const __hip_bfloat16* ks = Kb + (size_t)skey * QKVLD + sdh;
        pk0 = *reinterpret_cast<const int4*>(ks);
        pk1 = *reinterpret_cast<const int4*>(ks + 8);
        const __hip_bfloat16* vs = Vb + (size_t)skey * QKVLD + sdh;
        pv0 = *reinterpret_cast<const int4*>(vs);
        pv1 = *reinterpret_cast<const int4*>(vs + 8);
    }

    for (int kt = 0; kt < LSEQ / 128; ++kt) {
        const int k0 = kt * 128;
        __syncthreads();   // previous tile's Ks/Vt consumers done
        *reinterpret_cast<int4*>(&Ks[skey][sdh])     = pk0;
        *reinterpret_cast<int4*>(&Ks[skey][sdh + 8]) = pk1;
        {
            const __hip_bfloat16* vp0 = reinterpret_cast<const __hip_bfloat16*>(&pv0);
            const __hip_bfloat16* vp1 = reinterpret_cast<const __hip_bfloat16*>(&pv1);
#pragma unroll
            for (int jj = 0; jj < 8; ++jj) Vt[sdh + jj][vcol]     = vp0[jj];
#pragma unroll
            for (int jj = 0; jj < 8; ++jj) Vt[sdh + 8 + jj][vcol] = vp1[jj];
        }
        {
            const int knext = (kt + 1 < LSEQ / 128) ? k0 + 128 : k0;
            const __hip_bfloat16* ks = Kb + (size_t)(knext + skey) * QKVLD + sdh;
            pk0 = *reinterpret_cast<const int4*>(ks);
            pk1 = *reinterpret_cast<const int4*>(ks + 8);
            const __hip_bfloat16* vs = Vb + (size_t)(knext + skey) * QKVLD + sdh;
            pv0 = *reinterpret_cast<const int4*>(vs);
            pv1 = *reinterpret_cast<const int4*>(vs + 8);
        }
        __syncthreads();

        // 4 chunks of 32 keys: QK -> exp/pack -> PV, all register-resident
#pragma unroll
        for (int m = 0; m < 4; ++m) {
            short8 bkA0 = *reinterpret_cast<const short8*>(&Ks[(2*m)    *16 + l15][lq * 8]);
            short8 bkA1 = *reinterpret_cast<const short8*>(&Ks[(2*m)    *16 + l15][32 + lq * 8]);
            short8 bkB0 = *reinterpret_cast<const short8*>(&Ks[(2*m + 1)*16 + l15][lq * 8]);
            short8 bkB1 = *reinterpret_cast<const short8*>(&Ks[(2*m + 1)*16 + l15][32 + lq * 8]);
            float4v bvA = *reinterpret_cast<const float4v*>(bp + k0 + 32 * m);
            float4v bvB = *reinterpret_cast<const float4v*>(bp + k0 + 32 * m + 16);

            float4v sA = (float4v){0.f, 0.f, 0.f, 0.f};
            float4v sB = (float4v){0.f, 0.f, 0.f, 0.f};
            __builtin_amdgcn_s_setprio(1);
            sA = __builtin_amdgcn_mfma_f32_16x16x32_bf16(bkA0, aq[0], sA, 0, 0, 0);
            sA = __builtin_amdgcn_mfma_f32_16x16x32_bf16(bkA1, aq[1], sA, 0, 0, 0);
            sB = __builtin_amdgcn_mfma_f32_16x16x32_bf16(bkB0, aq[0], sB, 0, 0, 0);
            sB = __builtin_amdgcn_mfma_f32_16x16x32_bf16(bkB1, aq[1], sB, 0, 0, 0);
            __builtin_amdgcn_s_setprio(0);

            // p = exp(s + bias); lane-local pack into PV B-fragment.
            // pf element j: key 32m + (j>>2)*16 + 4lq + (j&3)
            union { __hip_bfloat16 hh[8]; short8 v; } pp;
#pragma unroll
            for (int r = 0; r < 4; ++r) {
                const float e = __expf(sA[r] + bvA[r]);
                lsum += e;
                pp.hh[r] = (__hip_bfloat16)e;
            }
#pragma unroll
            for (int r = 0; r < 4; ++r) {
                const float e = __expf(sB[r] + bvB[r]);
                lsum += e;
                pp.hh[4 + r] = (__hip_bfloat16)e;
            }
            const short8 pf = pp.v;

            // V^T fragments, slot order: one b128 per n, ^(n<<2) bank swizzle
            short8 vt[4];
#pragma unroll
            for (int n = 0; n < 4; ++n)
                vt[n] = *reinterpret_cast<const short8*>(
                    &Vt[n * 16 + l15][((m * 4 + lq) ^ (n << 2)) << 3]);

            __builtin_amdgcn_s_setprio(1);
#pragma unroll
            for (int n = 0; n < 4; ++n)
                o_acc[n] = __builtin_amdgcn_mfma_f32_16x16x32_bf16(
                    vt[n], pf, o_acc[n], 0, 0, 0);
            __builtin_amdgcn_s_setprio(0);
        }
    }

    // finalize l across the 4 lq groups sharing each q-row, then store.
    lsum += __shfl_xor(lsum, 16);
    lsum += __shfl_xor(lsum, 32);
    const float inv = 1.f / lsum;
    {
        const int row = q0 + w * 16 + l15;
        __hip_bfloat16* dst = X + (size_t)(b * LSEQ + row) * DMODEL + h * DHEAD + lq * 4;
#pragma unroll
        for (int n = 0; n < 4; ++n) {
            union { __hip_bfloat16 hh[4]; short4v v; } o;
#pragma unroll
            for (int r = 0; r < 4; ++r) o.hh[r] = (__hip_bfloat16)(o_acc[n][r] * inv);
            *reinterpret_cast<short4v*>(dst + n * 16) = o.v;
        }
    }
}

// ---------------------------------------------------------------------------
extern "C" void kernel_launch(void* const* d_in, const int* in_sizes, int n_in,
                              void* d_out, int out_size, void* d_ws, size_t ws_size,
                              hipStream_t stream)
{
    const float* qa   = (const float*)d_in[0];
    const float* ma   = (const float*)d_in[1];
    const float* bias = (const float*)d_in[2];
    const float* Wq   = (const float*)d_in[3];
    const float* Wk   = (const float*)d_in[4];
    const float* Wv   = (const float*)d_in[5];
    const float* Wo   = (const float*)d_in[6];
    float* out = (float*)d_out;

    // ws layout (48 MB): [0,8) qa16/Xw | [8,16) ma16 | [16,22) Wt | [22,24) Wot
    //                    | [24,48) QKVw[4096][3072]
    char* wsb = (char*)d_ws;
    __hip_bfloat16* qa16 = (__hip_bfloat16*)(wsb);
    __hip_bfloat16* ma16 = (__hip_bfloat16*)(wsb + (8u << 20));
    __hip_bfloat16* Wt   = (__hip_bfloat16*)(wsb + (16u << 20));
    __hip_bfloat16* Wot  = (__hip_bfloat16*)(wsb + (22u << 20));
    __hip_bfloat16* QKVw = (__hip_bfloat16*)(wsb + (24u << 20));
    __hip_bfloat16* Xw   = qa16;   // qa16 dead after QKV GEMM

    convert_kernel<<<dim3(MROWS * DMODEL / (256 * 8), 2), 256, 0, stream>>>(
        qa, ma, qa16, ma16);

    transpose_w_kernel<<<dim3(16, 16, 4), 256, 0, stream>>>(
        Wq, Wk, Wv, Wo,
        Wt, Wt + (size_t)DMODEL * DMODEL, Wt + 2 * (size_t)DMODEL * DMODEL, Wot);

    // QKV: M=4096, N=3072, K=1024. 1D grid 768 (24 n-tiles x 32 m-tiles).
    gemm_bt_kernel<<<dim3(768), 256, 0, stream>>>(
        qa16, ma16, DMODEL, 0.125f, 1.0f, Wt, nullptr, QKVw, DMODEL, QKVLD, 24);

    attn_mfma_kernel<<<dim3(512), 512, 0, stream>>>(QKVw, bias, Xw);

    // out-proj: M=4096, N=1024, K=1024. 1D grid 256 (8 n-tiles x 32 m-tiles).
    gemm_bt_kernel<<<dim3(256), 256, 0, stream>>>(
        Xw, Xw, DMODEL + 1, 1.0f, 1.0f, Wot, out, nullptr, DMODEL, DMODEL, 8);
}